// Round 1
// baseline (12901.588 us; speedup 1.0000x reference)
//
#include <hip/hip_runtime.h>
#include <math.h>

#define D_MODEL   768
#define N_LAYER   16
#define D_STATE   64
#define HEADDIM   64
#define D_INNER   1536
#define NHEADS    24
#define CONV_DIM  1664
#define D_IN_PROJ 3224
#define SEQLEN    2048
#define CHUNK     256
#define NCHUNK    8
#define VOCAB     32000

// ---------------- reduction helper (blockDim == 256) ----------------
__device__ __forceinline__ float block_sum(float v, float* red) {
#pragma unroll
  for (int off = 32; off > 0; off >>= 1) v += __shfl_down(v, off, 64);
  int wave = threadIdx.x >> 6;
  if ((threadIdx.x & 63) == 0) red[wave] = v;
  __syncthreads();
  return red[0] + red[1] + red[2] + red[3];
}

// ---------------- embedding gather ----------------
__global__ void embed_kernel(const int* __restrict__ ids, const float* __restrict__ emb,
                             float* __restrict__ x) {
  int t = blockIdx.x;
  int id = ids[t];
  const float* src = emb + (size_t)id * D_MODEL;
  float* dst = x + (size_t)t * D_MODEL;
  for (int i = threadIdx.x; i < D_MODEL; i += 256) dst[i] = src[i];
}

// ---------------- rmsnorm over 768 ----------------
__global__ __launch_bounds__(256) void rmsnorm_kernel(const float* __restrict__ x,
                                                      const float* __restrict__ w,
                                                      float* __restrict__ out) {
  __shared__ float red[4];
  int t = blockIdx.x;
  int tid = threadIdx.x;
  const float* row = x + (size_t)t * D_MODEL;
  float v0 = row[tid], v1 = row[tid + 256], v2 = row[tid + 512];
  float ss = block_sum(v0 * v0 + v1 * v1 + v2 * v2, red);
  float sc = rsqrtf(ss / (float)D_MODEL + 1e-6f);
  float* o = out + (size_t)t * D_MODEL;
  o[tid] = v0 * sc * w[tid];
  o[tid + 256] = v1 * sc * w[tid + 256];
  o[tid + 512] = v2 * sc * w[tid + 512];
}

// ---------------- fp32 GEMM: C[M,N] = A[M,K] * B[N,K]^T (+R) ----------------
// 128x128 tile, BK=16, 256 threads, 8x8 per thread.
template <int ADD>
__global__ __launch_bounds__(256) void gemm_bt_kernel(const float* __restrict__ A,
                                                      const float* __restrict__ B,
                                                      const float* __restrict__ R,
                                                      float* __restrict__ C,
                                                      int M, int N, int K) {
  __shared__ float As[16][132];
  __shared__ float Bs[16][132];
  int bm = blockIdx.y * 128, bn = blockIdx.x * 128;
  int tid = threadIdx.x;
  int tx = tid & 15, ty = tid >> 4;
  int lr = tid >> 1, lc = (tid & 1) * 8;
  float acc[8][8] = {};
  for (int k0 = 0; k0 < K; k0 += 16) {
    {
      int row = bm + lr;
      float4 v0 = make_float4(0.f, 0.f, 0.f, 0.f), v1 = v0;
      if (row < M) {
        const float* p = A + (size_t)row * K + k0 + lc;
        v0 = *(const float4*)p;
        v1 = *(const float4*)(p + 4);
      }
      As[lc + 0][lr] = v0.x; As[lc + 1][lr] = v0.y; As[lc + 2][lr] = v0.z; As[lc + 3][lr] = v0.w;
      As[lc + 4][lr] = v1.x; As[lc + 5][lr] = v1.y; As[lc + 6][lr] = v1.z; As[lc + 7][lr] = v1.w;
      int rowb = bn + lr;
      float4 w0 = make_float4(0.f, 0.f, 0.f, 0.f), w1 = w0;
      if (rowb < N) {
        const float* p = B + (size_t)rowb * K + k0 + lc;
        w0 = *(const float4*)p;
        w1 = *(const float4*)(p + 4);
      }
      Bs[lc + 0][lr] = w0.x; Bs[lc + 1][lr] = w0.y; Bs[lc + 2][lr] = w0.z; Bs[lc + 3][lr] = w0.w;
      Bs[lc + 4][lr] = w1.x; Bs[lc + 5][lr] = w1.y; Bs[lc + 6][lr] = w1.z; Bs[lc + 7][lr] = w1.w;
    }
    __syncthreads();
#pragma unroll
    for (int k = 0; k < 16; k++) {
      float a[8], b[8];
      *(float4*)&a[0] = *(const float4*)&As[k][ty * 8];
      *(float4*)&a[4] = *(const float4*)&As[k][ty * 8 + 4];
      *(float4*)&b[0] = *(const float4*)&Bs[k][tx * 8];
      *(float4*)&b[4] = *(const float4*)&Bs[k][tx * 8 + 4];
#pragma unroll
      for (int i = 0; i < 8; i++)
#pragma unroll
        for (int j = 0; j < 8; j++) acc[i][j] += a[i] * b[j];
    }
    __syncthreads();
  }
#pragma unroll
  for (int i = 0; i < 8; i++) {
    int row = bm + ty * 8 + i;
    if (row >= M) continue;
    size_t rb = (size_t)row * N;
#pragma unroll
    for (int j = 0; j < 8; j += 4) {
      int col = bn + tx * 8 + j;
      if (col >= N) continue;
      float4 v = make_float4(acc[i][j], acc[i][j + 1], acc[i][j + 2], acc[i][j + 3]);
      if (ADD) {
        float4 r = *(const float4*)(R + rb + col);
        v.x += r.x; v.y += r.y; v.z += r.z; v.w += r.w;
      }
      *(float4*)(C + rb + col) = v;
    }
  }
}

// ---------------- dt / dA ----------------
__global__ void dt_kernel(const float* __restrict__ zx, const float* __restrict__ dtb,
                          const float* __restrict__ alog, float* __restrict__ dt,
                          float* __restrict__ dAt) {
  int idx = blockIdx.x * 256 + threadIdx.x;
  if (idx >= SEQLEN * NHEADS) return;
  int l = idx / NHEADS, h = idx % NHEADS;
  float x = zx[(size_t)l * D_IN_PROJ + (D_IN_PROJ - NHEADS) + h] + dtb[h];
  float d = (x > 20.f) ? x : log1pf(expf(x));
  dt[idx] = d;
  dAt[h * SEQLEN + l] = -d * expf(alog[h]);
}

// ---------------- per-(chunk,head) inclusive cumsum of dA ----------------
__global__ __launch_bounds__(256) void cumsum_kernel(const float* __restrict__ dAt,
                                                     float* __restrict__ cum) {
  int c = blockIdx.x, h = blockIdx.y;
  int s = threadIdx.x;
  __shared__ float sc[256];
  sc[s] = dAt[h * SEQLEN + c * CHUNK + s];
  __syncthreads();
  for (int off = 1; off < 256; off <<= 1) {
    float t = (s >= off) ? sc[s - off] : 0.f;
    __syncthreads();
    sc[s] += t;
    __syncthreads();
  }
  cum[h * SEQLEN + c * CHUNK + s] = sc[s];
}

// ---------------- causal depthwise conv (k=4) + silu ----------------
__global__ void conv_silu_kernel(const float* __restrict__ zx, const float* __restrict__ w,
                                 const float* __restrict__ b, float* __restrict__ out) {
  int idx = blockIdx.x * 256 + threadIdx.x;
  if (idx >= SEQLEN * CONV_DIM) return;
  int l = idx / CONV_DIM, ch = idx % CONV_DIM;
  const float* col = zx + D_INNER + ch;
  float acc = b[ch];
#pragma unroll
  for (int k = 0; k < 4; k++) {
    int t = l - 3 + k;
    if (t >= 0) acc += col[(size_t)t * D_IN_PROJ] * w[ch * 4 + k];
  }
  out[idx] = acc / (1.f + expf(-acc));
}

// ---------------- per-chunk local states: states[p][n] = sum_s B[s,n]*decay[s]*xdt[s,p] ----
__global__ __launch_bounds__(256) void chunk_states_kernel(const float* __restrict__ convout,
                                                           const float* __restrict__ dt,
                                                           const float* __restrict__ cum,
                                                           float* __restrict__ lstates) {
  int c = blockIdx.x, h = blockIdx.y;
  int t = threadIdx.x;
  __shared__ float Bt[64][68];
  __shared__ float Xt[64][68];
  int p = t >> 2;
  int nb = (t & 3) * 16;
  float acc[16];
#pragma unroll
  for (int j = 0; j < 16; j++) acc[j] = 0.f;
  float cum_last = cum[h * SEQLEN + c * CHUNK + 255];
  for (int st = 0; st < 4; st++) {
    if (st) __syncthreads();
#pragma unroll
    for (int q = 0; q < 4; q++) {
      int flat = t * 16 + q * 4;
      int s = flat >> 6, col = flat & 63;
      int lg = c * CHUNK + st * 64 + s;
      const float* rowp = convout + (size_t)lg * CONV_DIM;
      *(float4*)&Bt[s][col] = *(const float4*)(rowp + D_INNER + col);
      float4 xv = *(const float4*)(rowp + h * HEADDIM + col);
      float wgt = dt[lg * NHEADS + h] * expf(cum_last - cum[h * SEQLEN + lg]);
      xv.x *= wgt; xv.y *= wgt; xv.z *= wgt; xv.w *= wgt;
      *(float4*)&Xt[s][col] = xv;
    }
    __syncthreads();
    for (int s = 0; s < 64; s++) {
      float xv = Xt[s][p];
#pragma unroll
      for (int j = 0; j < 16; j += 4) {
        float4 b = *(const float4*)&Bt[s][nb + j];
        acc[j] += xv * b.x; acc[j + 1] += xv * b.y;
        acc[j + 2] += xv * b.z; acc[j + 3] += xv * b.w;
      }
    }
  }
  float* out = lstates + (size_t)(c * NHEADS + h) * 4096 + p * 64 + nb;
#pragma unroll
  for (int j = 0; j < 16; j += 4)
    *(float4*)(out + j) = make_float4(acc[j], acc[j + 1], acc[j + 2], acc[j + 3]);
}

// ---------------- inter-chunk sequential scan: prev[c+1]=exp(a_c)*prev[c]+local[c] -------
__global__ void state_scan_kernel(const float* __restrict__ lstates,
                                  const float* __restrict__ cum,
                                  float* __restrict__ pstates) {
  int h = blockIdx.x;
  int e = blockIdx.y * 256 + threadIdx.x;
  float s = 0.f;
#pragma unroll
  for (int c = 0; c < NCHUNK; c++) {
    pstates[(size_t)(c * NHEADS + h) * 4096 + e] = s;
    float a = expf(cum[h * SEQLEN + c * CHUNK + 255]);
    s = s * a + lstates[(size_t)(c * NHEADS + h) * 4096 + e];
  }
}

// ---------------- Y = diag + off + D_skip*xs, per (chunk,head), thread = row l ----------
__global__ __launch_bounds__(256) void y_kernel(const float* __restrict__ convout,
                                                const float* __restrict__ dt,
                                                const float* __restrict__ cum,
                                                const float* __restrict__ pstates,
                                                const float* __restrict__ Dskip,
                                                float* __restrict__ y) {
  int c = blockIdx.x, h = blockIdx.y;
  int l = threadIdx.x;
  __shared__ float PS[64][68];   // transposed: PS[n][p]
  __shared__ float Bt[64][68];   // Bt[s][n]
  __shared__ float Xt[64][68];   // Xt[s][p] pre-scaled by dt
  __shared__ float cumsh[256];
  float Crow[64];
  {
    const float* cp = convout + (size_t)(c * CHUNK + l) * CONV_DIM + D_INNER + D_STATE;
#pragma unroll
    for (int n = 0; n < 64; n += 4) *(float4*)&Crow[n] = *(const float4*)(cp + n);
  }
  cumsh[l] = cum[h * SEQLEN + c * CHUNK + l];
  {
    const float* ps = pstates + (size_t)(c * NHEADS + h) * 4096;
#pragma unroll
    for (int q = 0; q < 16; q += 4) {
      int idx = l * 16 + q;
      int p = idx >> 6, n = idx & 63;
      float4 v = *(const float4*)(ps + idx);
      PS[n + 0][p] = v.x; PS[n + 1][p] = v.y; PS[n + 2][p] = v.z; PS[n + 3][p] = v.w;
    }
  }
  __syncthreads();
  float cum_l = cumsh[l];
  float acc[64];
#pragma unroll
  for (int p = 0; p < 64; p++) acc[p] = 0.f;
  // ---- Y_off: acc[p] += exp(cum_l) * sum_n C[l,n]*PS[n][p]
  {
    float el = expf(cum_l);
#pragma unroll
    for (int n = 0; n < 64; n++) {
      float coef = Crow[n] * el;
#pragma unroll
      for (int p = 0; p < 64; p += 4) {
        float4 v = *(const float4*)&PS[n][p];
        acc[p] += coef * v.x; acc[p + 1] += coef * v.y;
        acc[p + 2] += coef * v.z; acc[p + 3] += coef * v.w;
      }
    }
  }
  // ---- Y_diag: tiles of 64 s-rows
  for (int st = 0; st < 4; st++) {
    __syncthreads();
#pragma unroll
    for (int q = 0; q < 4; q++) {
      int flat = l * 16 + q * 4;
      int s = flat >> 6, col = flat & 63;
      int lg = c * CHUNK + st * 64 + s;
      const float* rowp = convout + (size_t)lg * CONV_DIM;
      *(float4*)&Bt[s][col] = *(const float4*)(rowp + D_INNER + col);
      float4 xv = *(const float4*)(rowp + h * HEADDIM + col);
      float wgt = dt[lg * NHEADS + h];
      xv.x *= wgt; xv.y *= wgt; xv.z *= wgt; xv.w *= wgt;
      *(float4*)&Xt[s][col] = xv;
    }
    __syncthreads();
    int base = st * 64;
    if (l >= base) {
      int smax = l - base;
      if (smax > 63) smax = 63;
      for (int s = 0; s <= smax; s++) {
        float dot = 0.f;
#pragma unroll
        for (int n = 0; n < 64; n += 4) {
          float4 b = *(const float4*)&Bt[s][n];
          dot += Crow[n] * b.x + Crow[n + 1] * b.y + Crow[n + 2] * b.z + Crow[n + 3] * b.w;
        }
        float coef = expf(cum_l - cumsh[base + s]) * dot;
#pragma unroll
        for (int p = 0; p < 64; p += 4) {
          float4 xv = *(const float4*)&Xt[s][p];
          acc[p] += coef * xv.x; acc[p + 1] += coef * xv.y;
          acc[p + 2] += coef * xv.z; acc[p + 3] += coef * xv.w;
        }
      }
    }
  }
  // ---- skip + store
  {
    float dsk = Dskip[h];
    const float* xsrow = convout + (size_t)(c * CHUNK + l) * CONV_DIM + h * HEADDIM;
    float* yrow = y + (size_t)(c * CHUNK + l) * D_INNER + h * HEADDIM;
#pragma unroll
    for (int p = 0; p < 64; p += 4) {
      float4 xv = *(const float4*)(xsrow + p);
      float4 v = make_float4(acc[p] + dsk * xv.x, acc[p + 1] + dsk * xv.y,
                             acc[p + 2] + dsk * xv.z, acc[p + 3] + dsk * xv.w);
      *(float4*)(yrow + p) = v;
    }
  }
}

// ---------------- gated rmsnorm over 1536: out = rmsnorm(y*silu(z)) * w ----------------
__global__ __launch_bounds__(256) void gated_rmsnorm_kernel(const float* __restrict__ y,
                                                            const float* __restrict__ zx,
                                                            const float* __restrict__ w,
                                                            float* __restrict__ out) {
  __shared__ float red[4];
  int t = blockIdx.x;
  int tid = threadIdx.x;
  const float* yr = y + (size_t)t * D_INNER;
  const float* zr = zx + (size_t)t * D_IN_PROJ;
  float v[6];
  float ss = 0.f;
#pragma unroll
  for (int i = 0; i < 6; i++) {
    int d = tid + i * 256;
    float z = zr[d];
    float val = yr[d] * (z / (1.f + expf(-z)));
    v[i] = val;
    ss += val * val;
  }
  float tot = block_sum(ss, red);
  float sc = rsqrtf(tot / (float)D_INNER + 1e-5f);
  float* o = out + (size_t)t * D_INNER;
#pragma unroll
  for (int i = 0; i < 6; i++) {
    int d = tid + i * 256;
    o[d] = v[i] * sc * w[d];
  }
}

// ---------------- launcher ----------------
extern "C" void kernel_launch(void* const* d_in, const int* in_sizes, int n_in,
                              void* d_out, int out_size, void* d_ws, size_t ws_size,
                              hipStream_t stream) {
  const int* ids = (const int*)d_in[0];
  const float* emb = (const float*)d_in[1];
  const float* ln_w = (const float*)d_in[2];
  const float* in_proj_w = (const float*)d_in[3];
  const float* conv_w = (const float*)d_in[4];
  const float* conv_b = (const float*)d_in[5];
  const float* dt_bias = (const float*)d_in[6];
  const float* A_log = (const float*)d_in[7];
  const float* D_skip = (const float*)d_in[8];
  const float* gnorm_w = (const float*)d_in[9];
  const float* out_proj_w = (const float*)d_in[10];
  const float* norm_f_w = (const float*)d_in[11];
  float* logits = (float*)d_out;

  float* ws = (float*)d_ws;
  float* x = ws;                                        // 2048*768
  float* hbuf = x + (size_t)SEQLEN * D_MODEL;           // 2048*768
  float* zx = hbuf + (size_t)SEQLEN * D_MODEL;          // 2048*3224
  float* convout = zx + (size_t)SEQLEN * D_IN_PROJ;     // 2048*1664
  float* dt = convout + (size_t)SEQLEN * CONV_DIM;      // 2048*24
  float* dAt = dt + SEQLEN * NHEADS;                    // 24*2048
  float* cum = dAt + SEQLEN * NHEADS;                   // 24*2048
  float* ybuf = cum + SEQLEN * NHEADS;                  // 2048*1536
  float* lstates = ybuf + (size_t)SEQLEN * D_INNER;     // 8*24*64*64
  float* pstates = lstates + (size_t)NCHUNK * NHEADS * HEADDIM * D_STATE;

  embed_kernel<<<SEQLEN, 256, 0, stream>>>(ids, emb, x);

  for (int i = 0; i < N_LAYER; i++) {
    rmsnorm_kernel<<<SEQLEN, 256, 0, stream>>>(x, ln_w + i * D_MODEL, hbuf);
    gemm_bt_kernel<0><<<dim3((D_IN_PROJ + 127) / 128, SEQLEN / 128), 256, 0, stream>>>(
        hbuf, in_proj_w + (size_t)i * D_IN_PROJ * D_MODEL, nullptr, zx,
        SEQLEN, D_IN_PROJ, D_MODEL);
    dt_kernel<<<(SEQLEN * NHEADS + 255) / 256, 256, 0, stream>>>(
        zx, dt_bias + i * NHEADS, A_log + i * NHEADS, dt, dAt);
    cumsum_kernel<<<dim3(NCHUNK, NHEADS), 256, 0, stream>>>(dAt, cum);
    conv_silu_kernel<<<(SEQLEN * CONV_DIM + 255) / 256, 256, 0, stream>>>(
        zx, conv_w + i * CONV_DIM * 4, conv_b + i * CONV_DIM, convout);
    chunk_states_kernel<<<dim3(NCHUNK, NHEADS), 256, 0, stream>>>(convout, dt, cum, lstates);
    state_scan_kernel<<<dim3(NHEADS, 16), 256, 0, stream>>>(lstates, cum, pstates);
    y_kernel<<<dim3(NCHUNK, NHEADS), 256, 0, stream>>>(
        convout, dt, cum, pstates, D_skip + i * NHEADS, ybuf);
    gated_rmsnorm_kernel<<<SEQLEN, 256, 0, stream>>>(ybuf, zx, gnorm_w + i * D_INNER, hbuf);
    gemm_bt_kernel<1><<<dim3(D_MODEL / 128, SEQLEN / 128), 256, 0, stream>>>(
        hbuf, out_proj_w + (size_t)i * D_MODEL * D_INNER, x, x,
        SEQLEN, D_MODEL, D_INNER);
  }

  rmsnorm_kernel<<<SEQLEN, 256, 0, stream>>>(x, norm_f_w, hbuf);
  gemm_bt_kernel<0><<<dim3(VOCAB / 128, SEQLEN / 128), 256, 0, stream>>>(
      hbuf, emb, nullptr, logits, SEQLEN, VOCAB, D_MODEL);
}

// Round 2
// 7118.468 us; speedup vs baseline: 1.8124x; 1.8124x over previous
//
#include <hip/hip_runtime.h>
#include <math.h>

#define D_MODEL   768
#define N_LAYER   16
#define D_STATE   64
#define HEADDIM   64
#define D_INNER   1536
#define NHEADS    24
#define CONV_DIM  1664
#define D_IN_PROJ 3224
#define SEQLEN    2048
#define CHUNK     256
#define NCHUNK    8
#define VOCAB     32000

typedef short bf16x8 __attribute__((ext_vector_type(8)));
typedef float f32x4 __attribute__((ext_vector_type(4)));

// round-to-nearest-even fp32 -> bf16 (as ushort)
__device__ __forceinline__ ushort f2bf(float f) {
  unsigned u = __float_as_uint(f);
  unsigned r = (u + 0x7FFFu + ((u >> 16) & 1u)) >> 16;
  return (ushort)r;
}

// ---------------- reduction helper (blockDim == 256) ----------------
__device__ __forceinline__ float block_sum(float v, float* red) {
#pragma unroll
  for (int off = 32; off > 0; off >>= 1) v += __shfl_down(v, off, 64);
  int wave = threadIdx.x >> 6;
  if ((threadIdx.x & 63) == 0) red[wave] = v;
  __syncthreads();
  return red[0] + red[1] + red[2] + red[3];
}

// ---------------- embedding gather ----------------
__global__ void embed_kernel(const int* __restrict__ ids, const float* __restrict__ emb,
                             float* __restrict__ x) {
  int t = blockIdx.x;
  int id = ids[t];
  const float* src = emb + (size_t)id * D_MODEL;
  float* dst = x + (size_t)t * D_MODEL;
  for (int i = threadIdx.x; i < D_MODEL; i += 256) dst[i] = src[i];
}

// ---------------- fp32 -> bf16 weight conversion with row zero-padding ----------------
__global__ void cvt_w_kernel(const float* __restrict__ src, ushort* __restrict__ dst,
                             int rows, int cols, int total_quads) {
  int i = blockIdx.x * 256 + threadIdx.x;
  if (i >= total_quads) return;
  int e = i * 4;
  int r = e / cols;
  ushort4 o;
  if (r < rows) {
    float4 v = *(const float4*)(src + e);
    o = make_ushort4(f2bf(v.x), f2bf(v.y), f2bf(v.z), f2bf(v.w));
  } else {
    o = make_ushort4(0, 0, 0, 0);
  }
  *(ushort4*)(dst + e) = o;
}

// ---------------- rmsnorm over 768, bf16 output ----------------
__global__ __launch_bounds__(256) void rmsnorm_kernel(const float* __restrict__ x,
                                                      const float* __restrict__ w,
                                                      ushort* __restrict__ out) {
  __shared__ float red[4];
  int t = blockIdx.x;
  int tid = threadIdx.x;
  const float* row = x + (size_t)t * D_MODEL;
  float v0 = row[tid], v1 = row[tid + 256], v2 = row[tid + 512];
  float ss = block_sum(v0 * v0 + v1 * v1 + v2 * v2, red);
  float sc = rsqrtf(ss / (float)D_MODEL + 1e-6f);
  ushort* o = out + (size_t)t * D_MODEL;
  o[tid] = f2bf(v0 * sc * w[tid]);
  o[tid + 256] = f2bf(v1 * sc * w[tid + 256]);
  o[tid + 512] = f2bf(v2 * sc * w[tid + 512]);
}

// ---------------- bf16 MFMA GEMM: C[M,N] = A[M,K] * B[N,K]^T (+R) ----------------
// 128x128 tile, BK=32, 256 threads = 4 waves, each wave 64x64 (4x4 MFMA tiles).
// LDS staged via global_load_lds width=16 with XOR swizzle slot = q ^ ((row>>1)&3).
template <int ADD>
__global__ __launch_bounds__(256) void gemm_mfma_kernel(const ushort* __restrict__ A,
                                                        const ushort* __restrict__ B,
                                                        const float* __restrict__ R,
                                                        float* __restrict__ C,
                                                        int N, int K) {
  __shared__ ushort Asm[128 * 32];
  __shared__ ushort Bsm[128 * 32];
  const int bm = blockIdx.y * 128, bn = blockIdx.x * 128;
  const int t = threadIdx.x;
  const int lane = t & 63;
  const int wave = t >> 6;
  const int wm = (wave & 1) * 64, wn = (wave >> 1) * 64;
  const int rl = lane & 15, quad = lane >> 4;

  // staging: thread t covers swizzled 16B chunks ci0 = t, ci1 = t+256 (for each matrix)
  const int ci0 = t, ci1 = t + 256;
  const int r0 = ci0 >> 2, q0 = (ci0 & 3) ^ ((r0 >> 1) & 3);
  const int r1 = ci1 >> 2, q1 = (ci1 & 3) ^ ((r1 >> 1) & 3);
  const ushort* Ag0 = A + (size_t)(bm + r0) * K + q0 * 8;
  const ushort* Ag1 = A + (size_t)(bm + r1) * K + q1 * 8;
  const ushort* Bg0 = B + (size_t)(bn + r0) * K + q0 * 8;
  const ushort* Bg1 = B + (size_t)(bn + r1) * K + q1 * 8;
  ushort* Al0 = Asm + ci0 * 8;
  ushort* Al1 = Asm + ci1 * 8;
  ushort* Bl0 = Bsm + ci0 * 8;
  ushort* Bl1 = Bsm + ci1 * 8;

  // fragment LDS offsets (ushort units), swizzle-consistent with staging
  int aoff[4], boff[4];
#pragma unroll
  for (int i = 0; i < 4; i++) {
    int ra = wm + i * 16 + rl;
    aoff[i] = ra * 32 + (quad ^ ((ra >> 1) & 3)) * 8;
    int rb = wn + i * 16 + rl;
    boff[i] = rb * 32 + (quad ^ ((rb >> 1) & 3)) * 8;
  }

  f32x4 acc[4][4];
#pragma unroll
  for (int i = 0; i < 4; i++)
#pragma unroll
    for (int j = 0; j < 4; j++) acc[i][j] = (f32x4)(0.f);

  for (int k0 = 0; k0 < K; k0 += 32) {
    __builtin_amdgcn_global_load_lds(
        (const __attribute__((address_space(1))) void*)(Ag0 + k0),
        (__attribute__((address_space(3))) void*)Al0, 16, 0, 0);
    __builtin_amdgcn_global_load_lds(
        (const __attribute__((address_space(1))) void*)(Ag1 + k0),
        (__attribute__((address_space(3))) void*)Al1, 16, 0, 0);
    __builtin_amdgcn_global_load_lds(
        (const __attribute__((address_space(1))) void*)(Bg0 + k0),
        (__attribute__((address_space(3))) void*)Bl0, 16, 0, 0);
    __builtin_amdgcn_global_load_lds(
        (const __attribute__((address_space(1))) void*)(Bg1 + k0),
        (__attribute__((address_space(3))) void*)Bl1, 16, 0, 0);
    __syncthreads();
    bf16x8 a[4], b[4];
#pragma unroll
    for (int i = 0; i < 4; i++) a[i] = *(const bf16x8*)(Asm + aoff[i]);
#pragma unroll
    for (int j = 0; j < 4; j++) b[j] = *(const bf16x8*)(Bsm + boff[j]);
#pragma unroll
    for (int i = 0; i < 4; i++)
#pragma unroll
      for (int j = 0; j < 4; j++)
        acc[i][j] = __builtin_amdgcn_mfma_f32_16x16x32_bf16(a[i], b[j], acc[i][j], 0, 0, 0);
    __syncthreads();
  }

  // epilogue: C/D layout col = lane&15, row = quad*4 + reg
#pragma unroll
  for (int mt = 0; mt < 4; mt++) {
#pragma unroll
    for (int reg = 0; reg < 4; reg++) {
      int row = bm + wm + mt * 16 + quad * 4 + reg;
      size_t rb = (size_t)row * N;
#pragma unroll
      for (int nt = 0; nt < 4; nt++) {
        int col = bn + wn + nt * 16 + rl;
        if (col < N) {
          float v = acc[mt][nt][reg];
          if (ADD) v += R[rb + col];
          C[rb + col] = v;
        }
      }
    }
  }
}

// ---------------- dt / dA ----------------
__global__ void dt_kernel(const float* __restrict__ zx, const float* __restrict__ dtb,
                          const float* __restrict__ alog, float* __restrict__ dt,
                          float* __restrict__ dAt) {
  int idx = blockIdx.x * 256 + threadIdx.x;
  if (idx >= SEQLEN * NHEADS) return;
  int l = idx / NHEADS, h = idx % NHEADS;
  float x = zx[(size_t)l * D_IN_PROJ + (D_IN_PROJ - NHEADS) + h] + dtb[h];
  float d = (x > 20.f) ? x : log1pf(expf(x));
  dt[idx] = d;
  dAt[h * SEQLEN + l] = -d * expf(alog[h]);
}

// ---------------- per-(chunk,head) inclusive cumsum of dA ----------------
__global__ __launch_bounds__(256) void cumsum_kernel(const float* __restrict__ dAt,
                                                     float* __restrict__ cum) {
  int c = blockIdx.x, h = blockIdx.y;
  int s = threadIdx.x;
  __shared__ float sc[256];
  sc[s] = dAt[h * SEQLEN + c * CHUNK + s];
  __syncthreads();
  for (int off = 1; off < 256; off <<= 1) {
    float t = (s >= off) ? sc[s - off] : 0.f;
    __syncthreads();
    sc[s] += t;
    __syncthreads();
  }
  cum[h * SEQLEN + c * CHUNK + s] = sc[s];
}

// ---------------- causal depthwise conv (k=4) + silu ----------------
__global__ void conv_silu_kernel(const float* __restrict__ zx, const float* __restrict__ w,
                                 const float* __restrict__ b, float* __restrict__ out) {
  int idx = blockIdx.x * 256 + threadIdx.x;
  if (idx >= SEQLEN * CONV_DIM) return;
  int l = idx / CONV_DIM, ch = idx % CONV_DIM;
  const float* col = zx + D_INNER + ch;
  float acc = b[ch];
#pragma unroll
  for (int k = 0; k < 4; k++) {
    int t = l - 3 + k;
    if (t >= 0) acc += col[(size_t)t * D_IN_PROJ] * w[ch * 4 + k];
  }
  out[idx] = acc / (1.f + expf(-acc));
}

// ---------------- per-chunk local states ----------------
__global__ __launch_bounds__(256) void chunk_states_kernel(const float* __restrict__ convout,
                                                           const float* __restrict__ dt,
                                                           const float* __restrict__ cum,
                                                           float* __restrict__ lstates) {
  int c = blockIdx.x, h = blockIdx.y;
  int t = threadIdx.x;
  __shared__ float Bt[64][68];
  __shared__ float Xt[64][68];
  int p = t >> 2;
  int nb = (t & 3) * 16;
  float acc[16];
#pragma unroll
  for (int j = 0; j < 16; j++) acc[j] = 0.f;
  float cum_last = cum[h * SEQLEN + c * CHUNK + 255];
  for (int st = 0; st < 4; st++) {
    if (st) __syncthreads();
#pragma unroll
    for (int q = 0; q < 4; q++) {
      int flat = t * 16 + q * 4;
      int s = flat >> 6, col = flat & 63;
      int lg = c * CHUNK + st * 64 + s;
      const float* rowp = convout + (size_t)lg * CONV_DIM;
      *(float4*)&Bt[s][col] = *(const float4*)(rowp + D_INNER + col);
      float4 xv = *(const float4*)(rowp + h * HEADDIM + col);
      float wgt = dt[lg * NHEADS + h] * expf(cum_last - cum[h * SEQLEN + lg]);
      xv.x *= wgt; xv.y *= wgt; xv.z *= wgt; xv.w *= wgt;
      *(float4*)&Xt[s][col] = xv;
    }
    __syncthreads();
    for (int s = 0; s < 64; s++) {
      float xv = Xt[s][p];
#pragma unroll
      for (int j = 0; j < 16; j += 4) {
        float4 b = *(const float4*)&Bt[s][nb + j];
        acc[j] += xv * b.x; acc[j + 1] += xv * b.y;
        acc[j + 2] += xv * b.z; acc[j + 3] += xv * b.w;
      }
    }
  }
  float* out = lstates + (size_t)(c * NHEADS + h) * 4096 + p * 64 + nb;
#pragma unroll
  for (int j = 0; j < 16; j += 4)
    *(float4*)(out + j) = make_float4(acc[j], acc[j + 1], acc[j + 2], acc[j + 3]);
}

// ---------------- inter-chunk sequential scan ----------------
__global__ void state_scan_kernel(const float* __restrict__ lstates,
                                  const float* __restrict__ cum,
                                  float* __restrict__ pstates) {
  int h = blockIdx.x;
  int e = blockIdx.y * 256 + threadIdx.x;
  float s = 0.f;
#pragma unroll
  for (int c = 0; c < NCHUNK; c++) {
    pstates[(size_t)(c * NHEADS + h) * 4096 + e] = s;
    float a = expf(cum[h * SEQLEN + c * CHUNK + 255]);
    s = s * a + lstates[(size_t)(c * NHEADS + h) * 4096 + e];
  }
}

// ---------------- Y = diag + off + D_skip*xs ----------------
__global__ __launch_bounds__(256) void y_kernel(const float* __restrict__ convout,
                                                const float* __restrict__ dt,
                                                const float* __restrict__ cum,
                                                const float* __restrict__ pstates,
                                                const float* __restrict__ Dskip,
                                                float* __restrict__ y) {
  int c = blockIdx.x, h = blockIdx.y;
  int l = threadIdx.x;
  __shared__ float PS[64][68];
  __shared__ float Bt[64][68];
  __shared__ float Xt[64][68];
  __shared__ float cumsh[256];
  float Crow[64];
  {
    const float* cp = convout + (size_t)(c * CHUNK + l) * CONV_DIM + D_INNER + D_STATE;
#pragma unroll
    for (int n = 0; n < 64; n += 4) *(float4*)&Crow[n] = *(const float4*)(cp + n);
  }
  cumsh[l] = cum[h * SEQLEN + c * CHUNK + l];
  {
    const float* ps = pstates + (size_t)(c * NHEADS + h) * 4096;
#pragma unroll
    for (int q = 0; q < 16; q += 4) {
      int idx = l * 16 + q;
      int p = idx >> 6, n = idx & 63;
      float4 v = *(const float4*)(ps + idx);
      PS[n + 0][p] = v.x; PS[n + 1][p] = v.y; PS[n + 2][p] = v.z; PS[n + 3][p] = v.w;
    }
  }
  __syncthreads();
  float cum_l = cumsh[l];
  float acc[64];
#pragma unroll
  for (int p = 0; p < 64; p++) acc[p] = 0.f;
  {
    float el = expf(cum_l);
#pragma unroll
    for (int n = 0; n < 64; n++) {
      float coef = Crow[n] * el;
#pragma unroll
      for (int p = 0; p < 64; p += 4) {
        float4 v = *(const float4*)&PS[n][p];
        acc[p] += coef * v.x; acc[p + 1] += coef * v.y;
        acc[p + 2] += coef * v.z; acc[p + 3] += coef * v.w;
      }
    }
  }
  for (int st = 0; st < 4; st++) {
    __syncthreads();
#pragma unroll
    for (int q = 0; q < 4; q++) {
      int flat = l * 16 + q * 4;
      int s = flat >> 6, col = flat & 63;
      int lg = c * CHUNK + st * 64 + s;
      const float* rowp = convout + (size_t)lg * CONV_DIM;
      *(float4*)&Bt[s][col] = *(const float4*)(rowp + D_INNER + col);
      float4 xv = *(const float4*)(rowp + h * HEADDIM + col);
      float wgt = dt[lg * NHEADS + h];
      xv.x *= wgt; xv.y *= wgt; xv.z *= wgt; xv.w *= wgt;
      *(float4*)&Xt[s][col] = xv;
    }
    __syncthreads();
    int base = st * 64;
    if (l >= base) {
      int smax = l - base;
      if (smax > 63) smax = 63;
      for (int s = 0; s <= smax; s++) {
        float dot = 0.f;
#pragma unroll
        for (int n = 0; n < 64; n += 4) {
          float4 b = *(const float4*)&Bt[s][n];
          dot += Crow[n] * b.x + Crow[n + 1] * b.y + Crow[n + 2] * b.z + Crow[n + 3] * b.w;
        }
        float coef = expf(cum_l - cumsh[base + s]) * dot;
#pragma unroll
        for (int p = 0; p < 64; p += 4) {
          float4 xv = *(const float4*)&Xt[s][p];
          acc[p] += coef * xv.x; acc[p + 1] += coef * xv.y;
          acc[p + 2] += coef * xv.z; acc[p + 3] += coef * xv.w;
        }
      }
    }
  }
  {
    float dsk = Dskip[h];
    const float* xsrow = convout + (size_t)(c * CHUNK + l) * CONV_DIM + h * HEADDIM;
    float* yrow = y + (size_t)(c * CHUNK + l) * D_INNER + h * HEADDIM;
#pragma unroll
    for (int p = 0; p < 64; p += 4) {
      float4 xv = *(const float4*)(xsrow + p);
      float4 v = make_float4(acc[p] + dsk * xv.x, acc[p + 1] + dsk * xv.y,
                             acc[p + 2] + dsk * xv.z, acc[p + 3] + dsk * xv.w);
      *(float4*)(yrow + p) = v;
    }
  }
}

// ---------------- gated rmsnorm over 1536, bf16 output ----------------
__global__ __launch_bounds__(256) void gated_rmsnorm_kernel(const float* __restrict__ y,
                                                            const float* __restrict__ zx,
                                                            const float* __restrict__ w,
                                                            ushort* __restrict__ out) {
  __shared__ float red[4];
  int t = blockIdx.x;
  int tid = threadIdx.x;
  const float* yr = y + (size_t)t * D_INNER;
  const float* zr = zx + (size_t)t * D_IN_PROJ;
  float v[6];
  float ss = 0.f;
#pragma unroll
  for (int i = 0; i < 6; i++) {
    int d = tid + i * 256;
    float z = zr[d];
    float val = yr[d] * (z / (1.f + expf(-z)));
    v[i] = val;
    ss += val * val;
  }
  float tot = block_sum(ss, red);
  float sc = rsqrtf(tot / (float)D_INNER + 1e-5f);
  ushort* o = out + (size_t)t * D_INNER;
#pragma unroll
  for (int i = 0; i < 6; i++) {
    int d = tid + i * 256;
    o[d] = f2bf(v[i] * sc * w[d]);
  }
}

// ---------------- launcher ----------------
extern "C" void kernel_launch(void* const* d_in, const int* in_sizes, int n_in,
                              void* d_out, int out_size, void* d_ws, size_t ws_size,
                              hipStream_t stream) {
  const int* ids = (const int*)d_in[0];
  const float* emb = (const float*)d_in[1];
  const float* ln_w = (const float*)d_in[2];
  const float* in_proj_w = (const float*)d_in[3];
  const float* conv_w = (const float*)d_in[4];
  const float* conv_b = (const float*)d_in[5];
  const float* dt_bias = (const float*)d_in[6];
  const float* A_log = (const float*)d_in[7];
  const float* D_skip = (const float*)d_in[8];
  const float* gnorm_w = (const float*)d_in[9];
  const float* out_proj_w = (const float*)d_in[10];
  const float* norm_f_w = (const float*)d_in[11];
  float* logits = (float*)d_out;

  float* ws = (float*)d_ws;
  float* x = ws;                                        // 2048*768
  float* zx = x + (size_t)SEQLEN * D_MODEL;             // 2048*3224
  float* convout = zx + (size_t)SEQLEN * D_IN_PROJ;     // 2048*1664
  float* dt = convout + (size_t)SEQLEN * CONV_DIM;      // 2048*24
  float* dAt = dt + SEQLEN * NHEADS;                    // 24*2048
  float* cum = dAt + SEQLEN * NHEADS;                   // 24*2048
  float* ybuf = cum + SEQLEN * NHEADS;                  // 2048*1536
  float* lstates = ybuf + (size_t)SEQLEN * D_INNER;     // 8*24*64*64
  float* pstates = lstates + (size_t)NCHUNK * NHEADS * HEADDIM * D_STATE;
  ushort* Abf = (ushort*)(pstates + (size_t)NCHUNK * NHEADS * HEADDIM * D_STATE); // 2048*1536 bf16
  ushort* Wbf = Abf + (size_t)SEQLEN * D_INNER;         // 3328*768 bf16 (layer weights, reused)
  ushort* EmbBf = Wbf + (size_t)3328 * D_MODEL;         // 32000*768 bf16

  // one-time per launch: emb -> bf16
  {
    int quads = VOCAB * D_MODEL / 4;
    cvt_w_kernel<<<(quads + 255) / 256, 256, 0, stream>>>(emb, EmbBf, VOCAB, D_MODEL, quads);
  }

  embed_kernel<<<SEQLEN, 256, 0, stream>>>(ids, emb, x);

  for (int i = 0; i < N_LAYER; i++) {
    rmsnorm_kernel<<<SEQLEN, 256, 0, stream>>>(x, ln_w + i * D_MODEL, Abf);
    {
      int quads = 3328 * D_MODEL / 4;
      cvt_w_kernel<<<(quads + 255) / 256, 256, 0, stream>>>(
          in_proj_w + (size_t)i * D_IN_PROJ * D_MODEL, Wbf, D_IN_PROJ, D_MODEL, quads);
    }
    gemm_mfma_kernel<0><<<dim3(26, 16), 256, 0, stream>>>(Abf, Wbf, nullptr, zx,
                                                          D_IN_PROJ, D_MODEL);
    dt_kernel<<<(SEQLEN * NHEADS + 255) / 256, 256, 0, stream>>>(
        zx, dt_bias + i * NHEADS, A_log + i * NHEADS, dt, dAt);
    cumsum_kernel<<<dim3(NCHUNK, NHEADS), 256, 0, stream>>>(dAt, cum);
    conv_silu_kernel<<<(SEQLEN * CONV_DIM + 255) / 256, 256, 0, stream>>>(
        zx, conv_w + i * CONV_DIM * 4, conv_b + i * CONV_DIM, convout);
    chunk_states_kernel<<<dim3(NCHUNK, NHEADS), 256, 0, stream>>>(convout, dt, cum, lstates);
    state_scan_kernel<<<dim3(NHEADS, 16), 256, 0, stream>>>(lstates, cum, pstates);
    y_kernel<<<dim3(NCHUNK, NHEADS), 256, 0, stream>>>(
        convout, dt, cum, pstates, D_skip + i * NHEADS, ybuf);
    gated_rmsnorm_kernel<<<SEQLEN, 256, 0, stream>>>(ybuf, zx, gnorm_w + i * D_INNER, Abf);
    {
      int quads = D_MODEL * D_INNER / 4;
      cvt_w_kernel<<<(quads + 255) / 256, 256, 0, stream>>>(
          out_proj_w + (size_t)i * D_MODEL * D_INNER, Wbf, D_MODEL, D_INNER, quads);
    }
    gemm_mfma_kernel<1><<<dim3(6, 16), 256, 0, stream>>>(Abf, Wbf, x, x,
                                                         D_MODEL, D_INNER);
  }

  rmsnorm_kernel<<<SEQLEN, 256, 0, stream>>>(x, norm_f_w, Abf);
  gemm_mfma_kernel<0><<<dim3(VOCAB / 128, SEQLEN / 128), 256, 0, stream>>>(
      Abf, EmbBf, nullptr, logits, VOCAB, D_MODEL);
}